// Round 3
// baseline (119.975 us; speedup 1.0000x reference)
//
#include <hip/hip_runtime.h>
#include <hip/hip_bf16.h>
#include <hip/hip_cooperative_groups.h>

namespace cg = cooperative_groups;

// out[b,i,j] = dot(head[b,i,:], W[:D]) + dot(dep[b,j,:], W[D:]) + b0
// B=16, S=1024, D=768. Memory-bound: 100.7 MB in + 67.1 MB out ~= 25.5 us floor.
// Single cooperative kernel: phase A (row dots) -> grid.sync -> phase B (broadcast add).

#define B_SZ 16
#define S_SZ 1024
#define D_SZ 768
#define NBLOCKS 1024
#define NTHREADS 256
#define ROWS (B_SZ * S_SZ)              // 16384
#define ROWS_PER_BLOCK (ROWS / NBLOCKS) // 16

typedef float fx4 __attribute__((ext_vector_type(4)));   // native vector: ok for nontemporal builtins

__global__ __launch_bounds__(NTHREADS, 4) void fused_affine_edge_kernel(
    const float* __restrict__ head,
    const float* __restrict__ dep,
    const float* __restrict__ edge_W,
    const float* __restrict__ edge_b,
    float* __restrict__ s,          // ws: [2*ROWS] floats
    float* __restrict__ out)
{
    const int lane   = threadIdx.x & 63;
    const int wid    = (blockIdx.x * NTHREADS + threadIdx.x) >> 6;  // 0..4095
    const int nwaves = (NBLOCKS * NTHREADS) >> 6;                   // 4096

    // ---- Phase A: 32768 row-dots (head rows then dep rows), one wave each ----
    const fx4* __restrict__ wp = reinterpret_cast<const fx4*>(edge_W);
    for (int r = wid; r < 2 * ROWS; r += nwaves) {
        const float* src;
        const fx4* wvec;
        int row;
        if (r < ROWS) { src = head; wvec = wp;              row = r; }
        else          { src = dep;  wvec = wp + (D_SZ / 4); row = r - ROWS; }

        const fx4* __restrict__ p =
            reinterpret_cast<const fx4*>(src + (size_t)row * D_SZ);
        float acc = 0.f;
#pragma unroll
        for (int k = 0; k < 3; ++k) {
            fx4 a = __builtin_nontemporal_load(&p[lane + k * 64]);
            fx4 b = wvec[lane + k * 64];
            acc += a.x * b.x + a.y * b.y + a.z * b.z + a.w * b.w;
        }
#pragma unroll
        for (int off = 32; off > 0; off >>= 1)
            acc += __shfl_down(acc, off, 64);
        if (lane == 0) s[r] = acc;
    }

    cg::this_grid().sync();

    // ---- Phase B: each block writes 16 consecutive rows (same batch b) ----
    const float bias = edge_b[0];
    const float* __restrict__ s_h = s;
    const float* __restrict__ s_d = s + ROWS;

    const int row0 = blockIdx.x * ROWS_PER_BLOCK;     // multiple of 16; same b
    const int b    = row0 >> 10;                      // S = 1024

    fx4 sd = reinterpret_cast<const fx4*>(s_d + ((size_t)b << 10))[threadIdx.x];
    sd.x += bias; sd.y += bias; sd.z += bias; sd.w += bias;

#pragma unroll
    for (int k = 0; k < ROWS_PER_BLOCK; ++k) {
        const float sh = s_h[row0 + k];
        fx4 o;
        o.x = sh + sd.x;
        o.y = sh + sd.y;
        o.z = sh + sd.z;
        o.w = sh + sd.w;
        fx4* dst = reinterpret_cast<fx4*>(out + ((size_t)(row0 + k) << 10));
        __builtin_nontemporal_store(o, &dst[threadIdx.x]);
    }
}

extern "C" void kernel_launch(void* const* d_in, const int* in_sizes, int n_in,
                              void* d_out, int out_size, void* d_ws, size_t ws_size,
                              hipStream_t stream) {
    const float* head   = (const float*)d_in[0];
    const float* dep    = (const float*)d_in[1];
    const float* edge_W = (const float*)d_in[2];
    const float* edge_b = (const float*)d_in[3];
    float* out = (float*)d_out;
    float* s   = (float*)d_ws;   // 2*16384 floats = 128 KiB

    void* args[] = { (void*)&head, (void*)&dep, (void*)&edge_W, (void*)&edge_b,
                     (void*)&s, (void*)&out };
    (void)hipLaunchCooperativeKernel((void*)fused_affine_edge_kernel,
                                     dim3(NBLOCKS), dim3(NTHREADS), args, 0, stream);
}

// Round 4
// 43.304 us; speedup vs baseline: 2.7705x; 2.7705x over previous
//
#include <hip/hip_runtime.h>
#include <hip/hip_bf16.h>

// out[b,i,j] = dot(head[b,i,:], W[:D]) + dot(dep[b,j,:], W[D:]) + b0
// B=16, S=1024, D=768. 100.7 MB read + 67.1 MB write => ~25.5 us floor @6.6 TB/s.
// Single fused kernel with per-batch producer/consumer sync (no cg::grid.sync —
// R3 showed it costs ~90 us via cache-maintenance + global spin).
// Sync design: relaxed agent atomics only (sc1, straight to L3 coherence point),
// explicit s_waitcnt vmcnt(0) for store->signal ordering. No buffer_inv/wbl2.

#define B_SZ 16
#define S_SZ 1024
#define D_SZ 768
#define NTHREADS 256
#define SUBS 64                   // blocks per batch
#define NBLOCKS (B_SZ * SUBS)     // 1024
#define ROWS_PB 16                // head rows (= dep rows) per block

typedef float fx4 __attribute__((ext_vector_type(4)));

__global__ __launch_bounds__(NTHREADS, 4) void fused_edge_kernel(
    const float* __restrict__ head,
    const float* __restrict__ dep,
    const float* __restrict__ edge_W,
    const float* __restrict__ edge_b,
    float* s_d,                    // ws: [B_SZ*S_SZ] dep dots
    unsigned int* cnt,             // ws: [B_SZ] arrival counters (memset 0 per call)
    float* __restrict__ out)
{
    const int b    = blockIdx.x >> 6;        // batch
    const int sub  = blockIdx.x & 63;
    const int wave = threadIdx.x >> 6;       // 0..3
    const int lane = threadIdx.x & 63;

    __shared__ float sh_local[ROWS_PB];

    const fx4* __restrict__ wph = reinterpret_cast<const fx4*>(edge_W);         // w_h
    const fx4* __restrict__ wpd = reinterpret_cast<const fx4*>(edge_W + D_SZ);  // w_d

    const size_t base = ((size_t)b << 10) + sub * ROWS_PB;   // global row index

    // ---- Phase A1: dep dots (cross-block data) — do these FIRST ----
    for (int k = wave; k < ROWS_PB; k += 4) {
        const fx4* __restrict__ p = reinterpret_cast<const fx4*>(dep + (base + k) * D_SZ);
        float acc = 0.f;
#pragma unroll
        for (int t = 0; t < 3; ++t) {
            fx4 a = p[lane + t * 64];
            fx4 w = wpd[lane + t * 64];
            acc += a.x * w.x + a.y * w.y + a.z * w.z + a.w * w.w;
        }
#pragma unroll
        for (int off = 32; off; off >>= 1) acc += __shfl_down(acc, off, 64);
        if (lane == 0)
            __hip_atomic_store(&s_d[base + k], acc,
                               __ATOMIC_RELAXED, __HIP_MEMORY_SCOPE_AGENT);
    }
    // each wave: its sc1 stores must be globally visible before the block signals
    asm volatile("s_waitcnt vmcnt(0)" ::: "memory");
    __syncthreads();
    if (threadIdx.x == 0)
        __hip_atomic_fetch_add(&cnt[b], 1u,
                               __ATOMIC_RELAXED, __HIP_MEMORY_SCOPE_AGENT);

    // ---- Phase A2: head dots (block-local, hides peers' latency) ----
    for (int k = wave; k < ROWS_PB; k += 4) {
        const fx4* __restrict__ p = reinterpret_cast<const fx4*>(head + (base + k) * D_SZ);
        float acc = 0.f;
#pragma unroll
        for (int t = 0; t < 3; ++t) {
            fx4 a = p[lane + t * 64];
            fx4 w = wph[lane + t * 64];
            acc += a.x * w.x + a.y * w.y + a.z * w.z + a.w * w.w;
        }
#pragma unroll
        for (int off = 32; off; off >>= 1) acc += __shfl_down(acc, off, 64);
        if (lane == 0) sh_local[k] = acc;
    }

    // ---- wait for all 64 producer blocks of batch b (relaxed poll, no inv) ----
    if (threadIdx.x == 0) {
        while (__hip_atomic_load(&cnt[b], __ATOMIC_RELAXED,
                                 __HIP_MEMORY_SCOPE_AGENT) < SUBS)
            __builtin_amdgcn_s_sleep(1);
    }
    __syncthreads();

    // ---- Phase B: out rows [base .. base+15], 256 threads x fx4 = 1024 j ----
    const float bias = edge_b[0];
    const float* sdb = s_d + ((size_t)b << 10);
    fx4 sd;
    {
        const int j = threadIdx.x * 4;
        // agent-scope relaxed loads: bypass L1/L2, guaranteed-fresh from L3
        sd.x = __hip_atomic_load(&sdb[j + 0], __ATOMIC_RELAXED, __HIP_MEMORY_SCOPE_AGENT);
        sd.y = __hip_atomic_load(&sdb[j + 1], __ATOMIC_RELAXED, __HIP_MEMORY_SCOPE_AGENT);
        sd.z = __hip_atomic_load(&sdb[j + 2], __ATOMIC_RELAXED, __HIP_MEMORY_SCOPE_AGENT);
        sd.w = __hip_atomic_load(&sdb[j + 3], __ATOMIC_RELAXED, __HIP_MEMORY_SCOPE_AGENT);
    }
    sd.x += bias; sd.y += bias; sd.z += bias; sd.w += bias;

#pragma unroll
    for (int k = 0; k < ROWS_PB; ++k) {
        const float sh = sh_local[k];
        fx4 o;
        o.x = sh + sd.x;
        o.y = sh + sd.y;
        o.z = sh + sd.z;
        o.w = sh + sd.w;
        fx4* dst = reinterpret_cast<fx4*>(out + (base + k) * (size_t)S_SZ);
        __builtin_nontemporal_store(o, &dst[threadIdx.x]);
    }
}

extern "C" void kernel_launch(void* const* d_in, const int* in_sizes, int n_in,
                              void* d_out, int out_size, void* d_ws, size_t ws_size,
                              hipStream_t stream) {
    const float* head   = (const float*)d_in[0];
    const float* dep    = (const float*)d_in[1];
    const float* edge_W = (const float*)d_in[2];
    const float* edge_b = (const float*)d_in[3];
    float* out = (float*)d_out;

    float*        s_d = (float*)d_ws;                                  // 64 KiB
    unsigned int* cnt = (unsigned int*)((char*)d_ws + (size_t)B_SZ * S_SZ * 4);

    // counters must be zero at kernel start every call (ws is poisoned 0xAA once)
    (void)hipMemsetAsync(cnt, 0, B_SZ * sizeof(unsigned int), stream);

    fused_edge_kernel<<<NBLOCKS, NTHREADS, 0, stream>>>(
        head, dep, edge_W, edge_b, s_d, cnt, out);
}

// Round 5
// 31.824 us; speedup vs baseline: 3.7699x; 1.3607x over previous
//
#include <hip/hip_runtime.h>
#include <hip/hip_bf16.h>

// out[b,i,j] = dot(head[b,i,:], W[:D]) + dot(dep[b,j,:], W[D:]) + b0
// B=16, S=1024, D=768.
// Two-kernel structure (R1: 31.8us) beat fused+sync (R4: 43us) and
// cg::grid.sync (R3: 120us). This round tunes the two kernels:
//  K1: 4 rows/wave, weights hoisted to regs, coalesced fx4 result store.
//  K2: 16 rows/block, s_d row cached in a register fx4, NT stores.

#define B_SZ 16
#define S_SZ 1024
#define D_SZ 768
#define ROWS (B_SZ * S_SZ)      // 16384 rows per input

typedef float fx4 __attribute__((ext_vector_type(4)));

// 2048 blocks x 256 = 8192 waves; waves 0..4095 -> head rows, 4096..8191 -> dep.
// Each wave computes 4 consecutive row-dots and stores them as one fx4.
__global__ __launch_bounds__(256) void dots_kernel(
    const float* __restrict__ head,
    const float* __restrict__ dep,
    const float* __restrict__ edge_W,
    float* __restrict__ s)           // [2*ROWS]: s_h then s_d
{
    const int gw   = (blockIdx.x * 256 + threadIdx.x) >> 6;   // 0..8191
    const int lane = threadIdx.x & 63;
    const int is_dep = gw >> 12;                              // 0: head, 1: dep
    const int base   = (gw & 4095) << 2;                      // first of 4 rows

    const float* __restrict__ src = is_dep ? dep : head;
    const fx4* __restrict__ wv =
        reinterpret_cast<const fx4*>(edge_W + (is_dep ? D_SZ : 0));

    // weights: 48 floats/lane half? no — 3 fx4 per lane, hoisted once per wave
    const fx4 w0 = wv[lane], w1 = wv[lane + 64], w2 = wv[lane + 128];

    float acc[4];
#pragma unroll
    for (int k = 0; k < 4; ++k) {
        const fx4* __restrict__ p =
            reinterpret_cast<const fx4*>(src + (size_t)(base + k) * D_SZ);
        fx4 a0 = p[lane], a1 = p[lane + 64], a2 = p[lane + 128];
        acc[k] = a0.x * w0.x + a0.y * w0.y + a0.z * w0.z + a0.w * w0.w
               + a1.x * w1.x + a1.y * w1.y + a1.z * w1.z + a1.w * w1.w
               + a2.x * w2.x + a2.y * w2.y + a2.z * w2.z + a2.w * w2.w;
    }

#pragma unroll
    for (int k = 0; k < 4; ++k)
#pragma unroll
        for (int off = 32; off; off >>= 1)
            acc[k] += __shfl_down(acc[k], off, 64);

    if (lane == 0) {
        fx4 o; o.x = acc[0]; o.y = acc[1]; o.z = acc[2]; o.w = acc[3];
        *reinterpret_cast<fx4*>(s + (is_dep ? ROWS : 0) + base) = o;
    }
}

// 1024 blocks x 16 consecutive rows (same batch). s_d[b,:] fx4 + bias cached
// in a register, reused for 16 row-writes. NT stores keep out of L2/L3.
__global__ __launch_bounds__(256) void bcast_kernel(
    const float* __restrict__ s,     // [2*ROWS]
    const float* __restrict__ edge_b,
    float* __restrict__ out)
{
    const int row0 = blockIdx.x << 4;        // multiple of 16, same b
    const int b    = row0 >> 10;             // S = 1024

    fx4 sd = reinterpret_cast<const fx4*>(s + ROWS + ((size_t)b << 10))[threadIdx.x];
    const float bias = edge_b[0];
    sd.x += bias; sd.y += bias; sd.z += bias; sd.w += bias;

#pragma unroll
    for (int k = 0; k < 16; ++k) {
        const float sh = s[row0 + k];
        fx4 o;
        o.x = sh + sd.x;
        o.y = sh + sd.y;
        o.z = sh + sd.z;
        o.w = sh + sd.w;
        fx4* dst = reinterpret_cast<fx4*>(out + ((size_t)(row0 + k) << 10));
        __builtin_nontemporal_store(o, &dst[threadIdx.x]);
    }
}

extern "C" void kernel_launch(void* const* d_in, const int* in_sizes, int n_in,
                              void* d_out, int out_size, void* d_ws, size_t ws_size,
                              hipStream_t stream) {
    const float* head   = (const float*)d_in[0];
    const float* dep    = (const float*)d_in[1];
    const float* edge_W = (const float*)d_in[2];
    const float* edge_b = (const float*)d_in[3];
    float* out = (float*)d_out;
    float* s   = (float*)d_ws;   // 2*16384 floats = 128 KiB

    dots_kernel<<<2048, 256, 0, stream>>>(head, dep, edge_W, s);
    bcast_kernel<<<ROWS / 16, 256, 0, stream>>>(s, edge_b, out);
}

// Round 6
// 30.587 us; speedup vs baseline: 3.9225x; 1.0405x over previous
//
#include <hip/hip_runtime.h>
#include <hip/hip_bf16.h>

// out[b,i,j] = dot(head[b,i,:], W[:D]) + dot(dep[b,j,:], W[D:]) + b0
// B=16, S=1024, D=768.
// R5 post-mortem: two different K1/K2 implementations both = 31.82us exactly
// -> memory/structure-bound, not instruction-bound.
// R6 rebalance: K1 = dep dots only (pure read, 50 MB).
//               K2 = head dots (block-local, 50 MB read) + output write (67 MB)
// so phase 2 mixes reads and writes on the bus instead of two serial
// unidirectional phases. Head dots never cross blocks -> no sync needed.

#define B_SZ 16
#define S_SZ 1024
#define D_SZ 768
#define ROWS (B_SZ * S_SZ)      // 16384 rows per input

typedef float fx4 __attribute__((ext_vector_type(4)));

// K1: dep dots. 4096 waves (1024 blocks x 256), 4 consecutive rows per wave.
__global__ __launch_bounds__(256) void dep_dots_kernel(
    const float* __restrict__ dep,
    const float* __restrict__ edge_W,
    float* __restrict__ s_d)         // [ROWS]
{
    const int gw   = (blockIdx.x * 256 + threadIdx.x) >> 6;   // 0..4095
    const int lane = threadIdx.x & 63;
    const int base = gw << 2;                                 // first of 4 rows

    const fx4* __restrict__ wv = reinterpret_cast<const fx4*>(edge_W + D_SZ);
    const fx4 w0 = wv[lane], w1 = wv[lane + 64], w2 = wv[lane + 128];

    float acc[4];
#pragma unroll
    for (int k = 0; k < 4; ++k) {
        const fx4* __restrict__ p =
            reinterpret_cast<const fx4*>(dep + (size_t)(base + k) * D_SZ);
        fx4 a0 = p[lane], a1 = p[lane + 64], a2 = p[lane + 128];
        acc[k] = a0.x * w0.x + a0.y * w0.y + a0.z * w0.z + a0.w * w0.w
               + a1.x * w1.x + a1.y * w1.y + a1.z * w1.z + a1.w * w1.w
               + a2.x * w2.x + a2.y * w2.y + a2.z * w2.z + a2.w * w2.w;
    }

#pragma unroll
    for (int k = 0; k < 4; ++k)
#pragma unroll
        for (int off = 32; off; off >>= 1)
            acc[k] += __shfl_down(acc[k], off, 64);

    if (lane == 0) {
        fx4 o; o.x = acc[0]; o.y = acc[1]; o.z = acc[2]; o.w = acc[3];
        *reinterpret_cast<fx4*>(s_d + base) = o;
    }
}

// K2: one block per 16 consecutive output rows (same batch b).
// Phase 1 (in-block): 4 waves x 4 rows -> 16 head dots into LDS.
// Phase 2: sd[b, 4j..4j+3] + bias cached in a register, 16 NT row-writes.
__global__ __launch_bounds__(256) void head_bcast_kernel(
    const float* __restrict__ head,
    const float* __restrict__ s_d,   // [ROWS]
    const float* __restrict__ edge_W,
    const float* __restrict__ edge_b,
    float* __restrict__ out)
{
    const int row0 = blockIdx.x << 4;        // multiple of 16, same b
    const int b    = row0 >> 10;             // S = 1024
    const int wave = threadIdx.x >> 6;       // 0..3
    const int lane = threadIdx.x & 63;

    __shared__ float sh[16];

    // head dots for rows row0..row0+15
    {
        const fx4* __restrict__ wv = reinterpret_cast<const fx4*>(edge_W);
        const fx4 w0 = wv[lane], w1 = wv[lane + 64], w2 = wv[lane + 128];
        const int base = row0 + (wave << 2);
        float acc[4];
#pragma unroll
        for (int k = 0; k < 4; ++k) {
            const fx4* __restrict__ p =
                reinterpret_cast<const fx4*>(head + (size_t)(base + k) * D_SZ);
            fx4 a0 = p[lane], a1 = p[lane + 64], a2 = p[lane + 128];
            acc[k] = a0.x * w0.x + a0.y * w0.y + a0.z * w0.z + a0.w * w0.w
                   + a1.x * w1.x + a1.y * w1.y + a1.z * w1.z + a1.w * w1.w
                   + a2.x * w2.x + a2.y * w2.y + a2.z * w2.z + a2.w * w2.w;
        }
#pragma unroll
        for (int k = 0; k < 4; ++k)
#pragma unroll
            for (int off = 32; off; off >>= 1)
                acc[k] += __shfl_down(acc[k], off, 64);
        if (lane == 0) {
#pragma unroll
            for (int k = 0; k < 4; ++k) sh[(wave << 2) + k] = acc[k];
        }
    }
    __syncthreads();

    // broadcast-add and write 16 rows
    fx4 sd = reinterpret_cast<const fx4*>(s_d + ((size_t)b << 10))[threadIdx.x];
    const float bias = edge_b[0];
    sd.x += bias; sd.y += bias; sd.z += bias; sd.w += bias;

#pragma unroll
    for (int k = 0; k < 16; ++k) {
        const float h = sh[k];
        fx4 o;
        o.x = h + sd.x;
        o.y = h + sd.y;
        o.z = h + sd.z;
        o.w = h + sd.w;
        fx4* dst = reinterpret_cast<fx4*>(out + ((size_t)(row0 + k) << 10));
        __builtin_nontemporal_store(o, &dst[threadIdx.x]);
    }
}

extern "C" void kernel_launch(void* const* d_in, const int* in_sizes, int n_in,
                              void* d_out, int out_size, void* d_ws, size_t ws_size,
                              hipStream_t stream) {
    const float* head   = (const float*)d_in[0];
    const float* dep    = (const float*)d_in[1];
    const float* edge_W = (const float*)d_in[2];
    const float* edge_b = (const float*)d_in[3];
    float* out = (float*)d_out;
    float* s_d = (float*)d_ws;   // 16384 floats = 64 KiB

    dep_dots_kernel<<<ROWS / 4 / 4, 256, 0, stream>>>(dep, edge_W, s_d);
    head_bcast_kernel<<<ROWS / 16, 256, 0, stream>>>(head, s_d, edge_W, edge_b, out);
}